// Round 12
// baseline (2482.359 us; speedup 1.0000x reference)
//
#include <hip/hip_runtime.h>
#include <cstdint>
#include <cstddef>

#define TOKENS 8192
#define DIN    4096
#define DOUT   4096

typedef int int4v  __attribute__((ext_vector_type(4)));
typedef int int16v __attribute__((ext_vector_type(16)));

// ---------------------------------------------------------------------------
// Kernel 1 (fused prep): blocks [0,16384) convert weight int32->int8 packed;
// blocks [16384, 24576) per-token dynamic quantization. One dispatch so the
// two memory-bound phases share HBM bandwidth instead of serializing.
// ---------------------------------------------------------------------------
__global__ __launch_bounds__(256) void prep(const float* __restrict__ x,
                                            const int* __restrict__ w,
                                            int* __restrict__ xq,
                                            int* __restrict__ w8,
                                            float* __restrict__ ascale,
                                            int* __restrict__ rsum) {
  __shared__ float wmax[4];
  __shared__ int   wsum[4];
  const int b = blockIdx.x;
  const int t = threadIdx.x;

  if (b < 16384) {                      // ---- wconv: 16384 blocks ----
    const int idx = b * 256 + t;        // one int4 (4 elems) each
    const int4 v = ((const int4*)w)[idx];
    w8[idx] = (v.x & 255) | ((v.y & 255) << 8) | ((v.z & 255) << 16) | ((v.w & 255) << 24);
    return;
  }

  // ---- quant: 8192 blocks, one per token row ----
  const int row = b - 16384;
  const float4* xr = (const float4*)(x + (size_t)row * DIN);
  float4 v[4];
#pragma unroll
  for (int i = 0; i < 4; ++i) v[i] = xr[i * 256 + t];

  float m = 0.f;
#pragma unroll
  for (int i = 0; i < 4; ++i) {
    m = fmaxf(m, fabsf(v[i].x)); m = fmaxf(m, fabsf(v[i].y));
    m = fmaxf(m, fabsf(v[i].z)); m = fmaxf(m, fabsf(v[i].w));
  }
#pragma unroll
  for (int off = 32; off; off >>= 1) m = fmaxf(m, __shfl_xor(m, off));

  const int lane = t & 63, wid = t >> 6;
  if (lane == 0) wmax[wid] = m;
  __syncthreads();
  m = fmaxf(fmaxf(wmax[0], wmax[1]), fmaxf(wmax[2], wmax[3]));

  const float s = m * (1.0f / 127.0f);
  const float sdiv = (m > 0.f) ? s : 1.0f;

  int ssum = 0;
#pragma unroll
  for (int i = 0; i < 4; ++i) {
    float q;
    q = fminf(fmaxf(rintf(v[i].x / sdiv), -127.f), 127.f); const int b0 = (int)q;
    q = fminf(fmaxf(rintf(v[i].y / sdiv), -127.f), 127.f); const int b1 = (int)q;
    q = fminf(fmaxf(rintf(v[i].z / sdiv), -127.f), 127.f); const int b2 = (int)q;
    q = fminf(fmaxf(rintf(v[i].w / sdiv), -127.f), 127.f); const int b3 = (int)q;
    ssum += b0 + b1 + b2 + b3;
    xq[(size_t)row * 1024 + i * 256 + t] =
        (b0 & 255) | ((b1 & 255) << 8) | ((b2 & 255) << 16) | ((b3 & 255) << 24);
  }
#pragma unroll
  for (int off = 32; off; off >>= 1) ssum += __shfl_xor(ssum, off);
  if (lane == 0) wsum[wid] = ssum;
  __syncthreads();
  if (t == 0) {
    rsum[row]   = wsum[0] + wsum[1] + wsum[2] + wsum[3];
    ascale[row] = s;
  }
}

// ---------------------------------------------------------------------------
// Kernel 2: i8 GEMM, 256x256 tile, 8 waves (2M x 4N), mfma_i32_32x32x32_i8.
// OCCUPANCY round: depth-2 LDS ring (64 KiB) -> 2 blocks/CU co-resident.
//  - grid 512 = 256 CU x 2 -> ALL blocks resident, no tail; the two blocks
//    on a CU are not barrier-coupled, so one block's MFMA phase fills the
//    other's read/barrier phase on the same SIMDs (m97 mechanism).
//  - per tile: stage T+1 into buf !(T&1) | RD k0,k1 | MFMA k0,k1 |
//    vmcnt(0)+barrier. WAR-safe: buf !(T&1) was last READ in tile T-1,
//    whose reads are register-consumed before the T-1 end barrier.
//  - R7-verified involution swizzle pair (staging source + fragment reads).
// ---------------------------------------------------------------------------
#define GLOAD(G_, L_) __builtin_amdgcn_global_load_lds(                       \
      (const __attribute__((address_space(1))) void*)(G_),                    \
      (__attribute__((address_space(3))) void*)(L_), 16, 0, 0)

#define STAGE(TT_)                                                            \
  do {                                                                        \
    char* Wb_ = lds + ((TT_) & 1) * 32768;                                    \
    const size_t ko_ = (size_t)(TT_) * 64;                                    \
    GLOAD(gA0 + ko_, Wb_ + ldst);                                             \
    GLOAD(gA1 + ko_, Wb_ + 8192 + ldst);                                      \
    GLOAD(gB0 + ko_, Wb_ + 16384 + ldst);                                     \
    GLOAD(gB1 + ko_, Wb_ + 24576 + ldst);                                     \
  } while (0)

#define RD(AV_, BV_, L_, AO_, BO_)                                            \
    _Pragma("unroll")                                                         \
    for (int mi = 0; mi < 4; ++mi)                                            \
      AV_[mi] = *(const int4v*)((L_) + (AO_) + mi * 2048);                    \
    _Pragma("unroll")                                                         \
    for (int ni = 0; ni < 2; ++ni)                                            \
      BV_[ni] = *(const int4v*)((L_) + (BO_) + ni * 2048);

#define MFMA8(AV_, BV_)                                                       \
  __builtin_amdgcn_s_setprio(1);                                              \
  _Pragma("unroll")                                                           \
  for (int mi = 0; mi < 4; ++mi) {                                            \
    acc[mi][0] = __builtin_amdgcn_mfma_i32_32x32x32_i8(AV_[mi], BV_[0], acc[mi][0], 0, 0, 0); \
    acc[mi][1] = __builtin_amdgcn_mfma_i32_32x32x32_i8(AV_[mi], BV_[1], acc[mi][1], 0, 0, 0); \
  }                                                                           \
  __builtin_amdgcn_s_setprio(0);

__global__ __launch_bounds__(512, 4) void gemm_i8(
    const char* __restrict__ xq, const char* __restrict__ w8,
    const float* __restrict__ ascale, const int* __restrict__ rsum,
    const float* __restrict__ wscale, const float* __restrict__ woff,
    const float* __restrict__ bias, float* __restrict__ y) {

  // 2 ring buffers x [Aunit0|Aunit1|Bunit0|Bunit1] x 8 KiB = 64 KiB
  __shared__ __align__(16) char lds[65536];

  const int bid = blockIdx.x;
  const int tm = bid >> 4;            // 32 M-tiles
  const int tn = bid & 15;            // 16 N-tiles
  const int t = threadIdx.x;          // 0..511
  const int lane = t & 63, wid = t >> 6;
  const int wmI = wid >> 2;           // 0..1 (M)
  const int wnI = wid & 3;            // 0..3 (N)

  // ---- staging source: involution (R7, verified passing) ----
  const int S_ = (t * 16) ^ (((t >> 3) & 3) << 4) ^ (((t >> 6) & 1) << 6);
  const int srow = S_ >> 6;                             // 0..127 within unit
  const int scol = S_ & 63;

  const char* gA0 = xq + (size_t)(tm * 256 + srow) * DIN + scol;
  const char* gA1 = gA0 + (size_t)128 * DIN;
  const char* gB0 = w8 + (size_t)(tn * 256 + srow) * DIN + scol;
  const char* gB1 = gB0 + (size_t)128 * DIN;
  const int ldst = t * 16;                              // LINEAR LDS dest

  // ---- fragment read offsets (R7 involution, verified passing) ----
  const int mask  = (((lane >> 1) & 3) << 4) ^ (((lane >> 4) & 1) << 6);
  const int arow  = (lane & 31) * 64 + (lane >> 5) * 16;
  const int aoff0 = wmI * 8192 + ((arow +  0) ^ mask);
  const int aoff1 = wmI * 8192 + ((arow + 32) ^ mask);
  const int brow  = (wnI & 1) * 4096 + arow;
  const int boff0 = (2 + (wnI >> 1)) * 8192 + ((brow +  0) ^ mask);
  const int boff1 = (2 + (wnI >> 1)) * 8192 + ((brow + 32) ^ mask);

  int16v acc[4][2];
#pragma unroll
  for (int mi = 0; mi < 4; ++mi)
#pragma unroll
    for (int ni = 0; ni < 2; ++ni)
#pragma unroll
      for (int rg = 0; rg < 16; ++rg) acc[mi][ni][rg] = 0;

  int4v aA[4], aB[4], bA[2], bB[2];

  // ---- prologue: stage tile 0; wait; enter loop ----
  STAGE(0);
  asm volatile("s_waitcnt vmcnt(0)" ::: "memory");
  __builtin_amdgcn_s_barrier();

  // ---- main loop: 64 K-tiles, depth-1 prefetch into the other buffer ----
  for (int T = 0; T < 64; ++T) {
    const char* Lb = lds + (T & 1) * 32768;
    if (T < 63) STAGE(T + 1);
    RD(aA, bA, Lb, aoff0, boff0)       /* k0(T) */
    RD(aB, bB, Lb, aoff1, boff1)       /* k1(T) */
    MFMA8(aA, bA)                      /* k0(T) */
    MFMA8(aB, bB)                      /* k1(T) */
    if (T < 63) {
      asm volatile("s_waitcnt vmcnt(0)" ::: "memory");
      __builtin_amdgcn_s_barrier();
    }
  }

  // ---- epilogue: zp-correction + dequant + bias ----
  // C/D 32x32: col = lane&31, row = (rg&3) + 8*(rg>>2) + 4*(lane>>5)
  const int rb0 = tm * 256 + wmI * 128 + 4 * (lane >> 5);
  const int cb0 = tn * 256 + wnI * 64 + (lane & 31);
  const float ws0 = wscale[cb0],      ws1 = wscale[cb0 + 32];
  const float wo0 = woff[cb0],        wo1 = woff[cb0 + 32];
  const float bi0 = bias[cb0],        bi1 = bias[cb0 + 32];
#pragma unroll
  for (int mi = 0; mi < 4; ++mi) {
#pragma unroll
    for (int rg = 0; rg < 16; ++rg) {
      const int r = rb0 + mi * 32 + (rg & 3) + 8 * (rg >> 2);
      const float as_ = ascale[r];
      const float rs_ = (float)rsum[r];
      y[(size_t)r * DOUT + cb0]      = ((float)acc[mi][0][rg] + rs_ * wo0) * (as_ * ws0) + bi0;
      y[(size_t)r * DOUT + cb0 + 32] = ((float)acc[mi][1][rg] + rs_ * wo1) * (as_ * ws1) + bi1;
    }
  }
}

// ---------------------------------------------------------------------------
extern "C" void kernel_launch(void* const* d_in, const int* in_sizes, int n_in,
                              void* d_out, int out_size, void* d_ws, size_t ws_size,
                              hipStream_t stream) {
  const float* x      = (const float*)d_in[0];
  const int*   w      = (const int*)  d_in[1];
  const float* wscale = (const float*)d_in[2];
  const float* woff   = (const float*)d_in[3];
  const float* bias   = (const float*)d_in[4];
  float* y = (float*)d_out;

  char* ws = (char*)d_ws;
  char*  xq     = ws;                                 // 33,554,432 B
  char*  w8     = ws + (size_t)TOKENS * DIN;          // 16,777,216 B
  float* ascale = (float*)(w8 + (size_t)DOUT * DIN);  // 32,768 B
  int*   rsum   = (int*)(ascale + TOKENS);            // 32,768 B

  hipLaunchKernelGGL(prep, dim3(16384 + TOKENS), dim3(256), 0, stream,
                     x, w, (int*)xq, (int*)w8, ascale, rsum);
  hipLaunchKernelGGL(gemm_i8, dim3((TOKENS / 256) * (DOUT / 256)), dim3(512), 0, stream,
                     xq, w8, ascale, rsum, wscale, woff, bias, y);
}

// Round 13
// 209.951 us; speedup vs baseline: 11.8235x; 11.8235x over previous
//
#include <hip/hip_runtime.h>
#include <cstdint>
#include <cstddef>

#define TOKENS 8192
#define DIN    4096
#define DOUT   4096

typedef int int4v  __attribute__((ext_vector_type(4)));
typedef int int16v __attribute__((ext_vector_type(16)));

// ---------------------------------------------------------------------------
// Kernel 1 (fused prep): blocks [0,16384) convert weight int32->int8 packed;
// blocks [16384, 24576) per-token dynamic quantization. One dispatch so the
// two memory-bound phases share HBM bandwidth instead of serializing.
// ---------------------------------------------------------------------------
__global__ __launch_bounds__(256) void prep(const float* __restrict__ x,
                                            const int* __restrict__ w,
                                            int* __restrict__ xq,
                                            int* __restrict__ w8,
                                            float* __restrict__ ascale,
                                            int* __restrict__ rsum) {
  __shared__ float wmax[4];
  __shared__ int   wsum[4];
  const int b = blockIdx.x;
  const int t = threadIdx.x;

  if (b < 16384) {                      // ---- wconv: 16384 blocks ----
    const int idx = b * 256 + t;        // one int4 (4 elems) each
    const int4 v = ((const int4*)w)[idx];
    w8[idx] = (v.x & 255) | ((v.y & 255) << 8) | ((v.z & 255) << 16) | ((v.w & 255) << 24);
    return;
  }

  // ---- quant: 8192 blocks, one per token row ----
  const int row = b - 16384;
  const float4* xr = (const float4*)(x + (size_t)row * DIN);
  float4 v[4];
#pragma unroll
  for (int i = 0; i < 4; ++i) v[i] = xr[i * 256 + t];

  float m = 0.f;
#pragma unroll
  for (int i = 0; i < 4; ++i) {
    m = fmaxf(m, fabsf(v[i].x)); m = fmaxf(m, fabsf(v[i].y));
    m = fmaxf(m, fabsf(v[i].z)); m = fmaxf(m, fabsf(v[i].w));
  }
#pragma unroll
  for (int off = 32; off; off >>= 1) m = fmaxf(m, __shfl_xor(m, off));

  const int lane = t & 63, wid = t >> 6;
  if (lane == 0) wmax[wid] = m;
  __syncthreads();
  m = fmaxf(fmaxf(wmax[0], wmax[1]), fmaxf(wmax[2], wmax[3]));

  const float s = m * (1.0f / 127.0f);
  const float sdiv = (m > 0.f) ? s : 1.0f;

  int ssum = 0;
#pragma unroll
  for (int i = 0; i < 4; ++i) {
    float q;
    q = fminf(fmaxf(rintf(v[i].x / sdiv), -127.f), 127.f); const int b0 = (int)q;
    q = fminf(fmaxf(rintf(v[i].y / sdiv), -127.f), 127.f); const int b1 = (int)q;
    q = fminf(fmaxf(rintf(v[i].z / sdiv), -127.f), 127.f); const int b2 = (int)q;
    q = fminf(fmaxf(rintf(v[i].w / sdiv), -127.f), 127.f); const int b3 = (int)q;
    ssum += b0 + b1 + b2 + b3;
    xq[(size_t)row * 1024 + i * 256 + t] =
        (b0 & 255) | ((b1 & 255) << 8) | ((b2 & 255) << 16) | ((b3 & 255) << 24);
  }
#pragma unroll
  for (int off = 32; off; off >>= 1) ssum += __shfl_xor(ssum, off);
  if (lane == 0) wsum[wid] = ssum;
  __syncthreads();
  if (t == 0) {
    rsum[row]   = wsum[0] + wsum[1] + wsum[2] + wsum[3];
    ascale[row] = s;
  }
}

// ---------------------------------------------------------------------------
// Kernel 2: i8 GEMM, 256x256 tile, 8 waves (2M x 4N), mfma_i32_32x32x32_i8.
// OCCUPANCY round, corrected: depth-2 LDS ring (64 KiB) -> 2 blocks/CU.
//  - __launch_bounds__(512, 2): R12's (512,4) capped the allocator at 64
//    VGPR -> acc spilled to scratch -> 12.6 GB HBM traffic, 2478 us. With
//    (512,2) the allocator gives 224 regs/wave (no spill) and 2 blocks/CU
//    still co-reside because LDS is the binding resource (2x64 <= 160 KiB;
//    regs: 4 waves/SIMD x 224 = 896 <= 2048).
//  - The two blocks on a CU are not barrier-coupled: one block's MFMA phase
//    fills the other's stage/read/barrier phase on the same SIMDs.
//  - per tile: stage T+1 into buf !(T&1) | RD k0,k1 | MFMA k0,k1 |
//    vmcnt(0)+barrier. WAR-safe: buf !(T&1) was last READ in tile T-1,
//    whose reads are register-consumed before the T-1 end barrier.
//  - R7-verified involution swizzle pair (staging source + fragment reads).
// ---------------------------------------------------------------------------
#define GLOAD(G_, L_) __builtin_amdgcn_global_load_lds(                       \
      (const __attribute__((address_space(1))) void*)(G_),                    \
      (__attribute__((address_space(3))) void*)(L_), 16, 0, 0)

#define STAGE(TT_)                                                            \
  do {                                                                        \
    char* Wb_ = lds + ((TT_) & 1) * 32768;                                    \
    const size_t ko_ = (size_t)(TT_) * 64;                                    \
    GLOAD(gA0 + ko_, Wb_ + ldst);                                             \
    GLOAD(gA1 + ko_, Wb_ + 8192 + ldst);                                      \
    GLOAD(gB0 + ko_, Wb_ + 16384 + ldst);                                     \
    GLOAD(gB1 + ko_, Wb_ + 24576 + ldst);                                     \
  } while (0)

#define RD(AV_, BV_, L_, AO_, BO_)                                            \
    _Pragma("unroll")                                                         \
    for (int mi = 0; mi < 4; ++mi)                                            \
      AV_[mi] = *(const int4v*)((L_) + (AO_) + mi * 2048);                    \
    _Pragma("unroll")                                                         \
    for (int ni = 0; ni < 2; ++ni)                                            \
      BV_[ni] = *(const int4v*)((L_) + (BO_) + ni * 2048);

#define MFMA8(AV_, BV_)                                                       \
  __builtin_amdgcn_s_setprio(1);                                              \
  _Pragma("unroll")                                                           \
  for (int mi = 0; mi < 4; ++mi) {                                            \
    acc[mi][0] = __builtin_amdgcn_mfma_i32_32x32x32_i8(AV_[mi], BV_[0], acc[mi][0], 0, 0, 0); \
    acc[mi][1] = __builtin_amdgcn_mfma_i32_32x32x32_i8(AV_[mi], BV_[1], acc[mi][1], 0, 0, 0); \
  }                                                                           \
  __builtin_amdgcn_s_setprio(0);

__global__ __launch_bounds__(512, 2) void gemm_i8(
    const char* __restrict__ xq, const char* __restrict__ w8,
    const float* __restrict__ ascale, const int* __restrict__ rsum,
    const float* __restrict__ wscale, const float* __restrict__ woff,
    const float* __restrict__ bias, float* __restrict__ y) {

  // 2 ring buffers x [Aunit0|Aunit1|Bunit0|Bunit1] x 8 KiB = 64 KiB
  __shared__ __align__(16) char lds[65536];

  const int bid = blockIdx.x;
  const int tm = bid >> 4;            // 32 M-tiles
  const int tn = bid & 15;            // 16 N-tiles
  const int t = threadIdx.x;          // 0..511
  const int lane = t & 63, wid = t >> 6;
  const int wmI = wid >> 2;           // 0..1 (M)
  const int wnI = wid & 3;            // 0..3 (N)

  // ---- staging source: involution (R7, verified passing) ----
  const int S_ = (t * 16) ^ (((t >> 3) & 3) << 4) ^ (((t >> 6) & 1) << 6);
  const int srow = S_ >> 6;                             // 0..127 within unit
  const int scol = S_ & 63;

  const char* gA0 = xq + (size_t)(tm * 256 + srow) * DIN + scol;
  const char* gA1 = gA0 + (size_t)128 * DIN;
  const char* gB0 = w8 + (size_t)(tn * 256 + srow) * DIN + scol;
  const char* gB1 = gB0 + (size_t)128 * DIN;
  const int ldst = t * 16;                              // LINEAR LDS dest

  // ---- fragment read offsets (R7 involution, verified passing) ----
  const int mask  = (((lane >> 1) & 3) << 4) ^ (((lane >> 4) & 1) << 6);
  const int arow  = (lane & 31) * 64 + (lane >> 5) * 16;
  const int aoff0 = wmI * 8192 + ((arow +  0) ^ mask);
  const int aoff1 = wmI * 8192 + ((arow + 32) ^ mask);
  const int brow  = (wnI & 1) * 4096 + arow;
  const int boff0 = (2 + (wnI >> 1)) * 8192 + ((brow +  0) ^ mask);
  const int boff1 = (2 + (wnI >> 1)) * 8192 + ((brow + 32) ^ mask);

  int16v acc[4][2];
#pragma unroll
  for (int mi = 0; mi < 4; ++mi)
#pragma unroll
    for (int ni = 0; ni < 2; ++ni)
#pragma unroll
      for (int rg = 0; rg < 16; ++rg) acc[mi][ni][rg] = 0;

  int4v aA[4], aB[4], bA[2], bB[2];

  // ---- prologue: stage tile 0; wait; enter loop ----
  STAGE(0);
  asm volatile("s_waitcnt vmcnt(0)" ::: "memory");
  __builtin_amdgcn_s_barrier();

  // ---- main loop: 64 K-tiles, depth-1 prefetch into the other buffer ----
  for (int T = 0; T < 64; ++T) {
    const char* Lb = lds + (T & 1) * 32768;
    if (T < 63) STAGE(T + 1);
    RD(aA, bA, Lb, aoff0, boff0)       /* k0(T) */
    RD(aB, bB, Lb, aoff1, boff1)       /* k1(T) */
    MFMA8(aA, bA)                      /* k0(T) */
    MFMA8(aB, bB)                      /* k1(T) */
    if (T < 63) {
      asm volatile("s_waitcnt vmcnt(0)" ::: "memory");
      __builtin_amdgcn_s_barrier();
    }
  }

  // ---- epilogue: zp-correction + dequant + bias ----
  // C/D 32x32: col = lane&31, row = (rg&3) + 8*(rg>>2) + 4*(lane>>5)
  const int rb0 = tm * 256 + wmI * 128 + 4 * (lane >> 5);
  const int cb0 = tn * 256 + wnI * 64 + (lane & 31);
  const float ws0 = wscale[cb0],      ws1 = wscale[cb0 + 32];
  const float wo0 = woff[cb0],        wo1 = woff[cb0 + 32];
  const float bi0 = bias[cb0],        bi1 = bias[cb0 + 32];
#pragma unroll
  for (int mi = 0; mi < 4; ++mi) {
#pragma unroll
    for (int rg = 0; rg < 16; ++rg) {
      const int r = rb0 + mi * 32 + (rg & 3) + 8 * (rg >> 2);
      const float as_ = ascale[r];
      const float rs_ = (float)rsum[r];
      y[(size_t)r * DOUT + cb0]      = ((float)acc[mi][0][rg] + rs_ * wo0) * (as_ * ws0) + bi0;
      y[(size_t)r * DOUT + cb0 + 32] = ((float)acc[mi][1][rg] + rs_ * wo1) * (as_ * ws1) + bi1;
    }
  }
}

// ---------------------------------------------------------------------------
extern "C" void kernel_launch(void* const* d_in, const int* in_sizes, int n_in,
                              void* d_out, int out_size, void* d_ws, size_t ws_size,
                              hipStream_t stream) {
  const float* x      = (const float*)d_in[0];
  const int*   w      = (const int*)  d_in[1];
  const float* wscale = (const float*)d_in[2];
  const float* woff   = (const float*)d_in[3];
  const float* bias   = (const float*)d_in[4];
  float* y = (float*)d_out;

  char* ws = (char*)d_ws;
  char*  xq     = ws;                                 // 33,554,432 B
  char*  w8     = ws + (size_t)TOKENS * DIN;          // 16,777,216 B
  float* ascale = (float*)(w8 + (size_t)DOUT * DIN);  // 32,768 B
  int*   rsum   = (int*)(ascale + TOKENS);            // 32,768 B

  hipLaunchKernelGGL(prep, dim3(16384 + TOKENS), dim3(256), 0, stream,
                     x, w, (int*)xq, (int*)w8, ascale, rsum);
  hipLaunchKernelGGL(gemm_i8, dim3((TOKENS / 256) * (DOUT / 256)), dim3(512), 0, stream,
                     xq, w8, ascale, rsum, wscale, woff, bias, y);
}